// Round 1
// baseline (371.948 us; speedup 1.0000x reference)
//
#include <hip/hip_runtime.h>

// GCNN fused kernel for MI355X (gfx950).
// Structure: per-sentence block (64 rows), bf16 MFMA GEMM C[64,512] = A @ [W_in|W_self],
// fp32 gate dot-products, in-LDS head-gather epilogue. W pre-transposed to bf16 in ws.

#define BNK   1280
#define LTOK  64
#define DIN   512
#define DOUT  256
#define NCAT  512          // DOUT*2 (concat of W_in and W_self columns)
#define TPB   512
#define BK    32
#define NCHUNK (DIN / BK)  // 16
#define A_STRIDE 56        // bf16 elems per A row in LDS: 32 data + pad (112B, 16B-aligned, 2-way banks)

typedef __attribute__((ext_vector_type(4))) float f32x4;
typedef __attribute__((ext_vector_type(8))) short s16x8;

__device__ __forceinline__ unsigned short f2bf(float f) {
  // round-to-nearest-even f32 -> bf16
  unsigned u = __float_as_uint(f);
  unsigned r = (u + 0x7FFFu + ((u >> 16) & 1u)) >> 16;
  return (unsigned short)r;
}
__device__ __forceinline__ float bf2f(unsigned short h) {
  return __uint_as_float(((unsigned)h) << 16);
}
__device__ __forceinline__ float sigmoidf_(float x) {
  return 1.0f / (1.0f + __expf(-x));
}

// ---------------- kernel 0: W_cat -> bf16, transposed to [cat_col][k] ----------------
__global__ __launch_bounds__(256) void wprep_kernel(const float* __restrict__ W_in,
                                                    const float* __restrict__ W_self,
                                                    unsigned short* __restrict__ Wt) {
  __shared__ float tile[32][33];
  const int t  = threadIdx.x;
  const int c0 = (blockIdx.x & 15) * 32;   // cat col tile
  const int k0 = (blockIdx.x >> 4) * 32;   // k tile
  const float* src = (c0 < DOUT) ? W_in : W_self;
  const int cadj   = (c0 < DOUT) ? c0 : (c0 - DOUT);
  {
    const int kk = t >> 3;
    const int cc = (t & 7) * 4;
    const float4 v = *(const float4*)(src + (size_t)(k0 + kk) * DOUT + cadj + cc);
    tile[kk][cc + 0] = v.x; tile[kk][cc + 1] = v.y;
    tile[kk][cc + 2] = v.z; tile[kk][cc + 3] = v.w;
  }
  __syncthreads();
  {
    const int cc = t >> 3;
    const int kk = (t & 7) * 4;
    ushort4 o;
    o.x = f2bf(tile[kk + 0][cc]); o.y = f2bf(tile[kk + 1][cc]);
    o.z = f2bf(tile[kk + 2][cc]); o.w = f2bf(tile[kk + 3][cc]);
    *(ushort4*)(Wt + (size_t)(c0 + cc) * DIN + k0 + kk) = o;
  }
}

// ---------------- main fused kernel ----------------
// LDS union layout (bytes), total 41728:
//   GEMM phase:    As [64][56] bf16 @ 0 (7168) | Ws [512][32] bf16 (swizzled) @ 7168 (32768)
//   pre phase:     wgi[512] f32 @ 0 | wgs[512] f32 @ 2048 | part[512][2] f32 @ 4096
//   epilogue:      Pin [64][128] bf16 @ 0 (16384) | Psf [64][128] bf16 @ 16384 (16384)
//   persistent:    gld[64][2] @ 39936 | winl @ 40448 | wsfl @ 40704 | mskl @ 40960
//                  hdl @ 41216 | lbl @ 41472
__global__ __launch_bounds__(TPB) void gcn_kernel(
    const float* __restrict__ rep,
    const float* __restrict__ adj_mask_in,
    const float* __restrict__ adj_mask_loop,
    const float* __restrict__ maskp,
    const float* __restrict__ b_in,
    const float* __restrict__ w_gate_in,
    const float* __restrict__ b_gate_in,
    const float* __restrict__ w_gate_self,
    const int* __restrict__ arc,
    const int* __restrict__ lab,
    const unsigned short* __restrict__ Wt,
    float* __restrict__ out)
{
  __shared__ __align__(16) char smem[41728];
  unsigned short* As  = (unsigned short*)(smem);
  unsigned short* Ws  = (unsigned short*)(smem + 7168);
  unsigned short* Pin = (unsigned short*)(smem);
  unsigned short* Psf = (unsigned short*)(smem + 16384);
  float* wgi  = (float*)(smem);
  float* wgs  = (float*)(smem + 2048);
  float* part = (float*)(smem + 4096);
  float* gld  = (float*)(smem + 39936);
  float* winl = (float*)(smem + 40448);
  float* wsfl = (float*)(smem + 40704);
  float* mskl = (float*)(smem + 40960);
  int*   hdl  = (int*)(smem + 41216);
  int*   lbl  = (int*)(smem + 41472);

  const int b    = blockIdx.x;     // sentence
  const int t    = threadIdx.x;
  const int wave = t >> 6;
  const int lane = t & 63;
  const int nlo  = lane & 15;
  const int quad = lane >> 4;

  // ---- pre-phase: raw gates in fp32 (sigmoid-sensitive; keep full precision) ----
  wgi[t] = w_gate_in[t];
  wgs[t] = w_gate_self[t];
  __syncthreads();
  {
    const int r = t >> 3, p = t & 7;
    const float* row = rep + (size_t)(b * LTOK + r) * DIN;
    float si = 0.f, ss = 0.f;
    #pragma unroll 8
    for (int j = 0; j < 64; ++j) {
      const int k = p + j * 8;          // coalesced across the 8 threads of a row
      const float a = row[k];
      si += a * wgi[k];
      ss += a * wgs[k];
    }
    part[t * 2 + 0] = si;
    part[t * 2 + 1] = ss;
  }
  __syncthreads();
  if (t < 128) {
    const int r = t >> 1, g = t & 1;
    float s = 0.f;
    #pragma unroll
    for (int p = 0; p < 8; ++p) s += part[(r * 8 + p) * 2 + g];
    gld[r * 2 + g] = s;
  }

  // ---- GEMM: acc[mt][nt] covers rows mt*16.., cat cols wave*64 + nt*16.. ----
  f32x4 acc[4][4];
  #pragma unroll
  for (int i = 0; i < 4; ++i)
    #pragma unroll
    for (int j = 0; j < 4; ++j) {
      f32x4 z = {0.f, 0.f, 0.f, 0.f};
      acc[i][j] = z;
    }

  for (int kc = 0; kc < NCHUNK; ++kc) {
    __syncthreads();   // previous chunk's fragment reads (or pre-phase) done
    const int k0 = kc * BK;

    // async stage W chunk [512 cols][32 k] bf16 via global_load_lds (16B units).
    // XOR swizzle in the SOURCE address: LDS unit (c, p) holds logical k-quad q = p ^ ((c>>1)&3),
    // so lane-contiguous LDS placement is preserved and B-frag reads are 2-way (free).
    #pragma unroll
    for (int i = 0; i < 4; ++i) {
      const int u = i * TPB + t;
      const int c = u >> 2;
      const int p = u & 3;
      const int q = p ^ ((c >> 1) & 3);
      const unsigned short* g = Wt + (size_t)c * DIN + k0 + q * 8;
      __builtin_amdgcn_global_load_lds(
          (const __attribute__((address_space(1))) void*)g,
          (__attribute__((address_space(3))) void*)(smem + 7168 + u * 16),
          16, 0, 0);
    }

    // stage A chunk with fp32 -> bf16 convert (rep row b*64+r, k0+kk..+3)
    {
      const int r  = t >> 3;
      const int kk = (t & 7) * 4;
      const float4 v = *(const float4*)(rep + (size_t)(b * LTOK + r) * DIN + k0 + kk);
      ushort4 o;
      o.x = f2bf(v.x); o.y = f2bf(v.y); o.z = f2bf(v.z); o.w = f2bf(v.w);
      *(ushort4*)(As + r * A_STRIDE + kk) = o;
    }
    __syncthreads();   // staging visible (drains vmcnt for global_load_lds too)

    // A fragments: A[m = lane&15][k = quad*8 + j]
    s16x8 af[4];
    #pragma unroll
    for (int mt = 0; mt < 4; ++mt)
      af[mt] = *(const s16x8*)(As + (mt * 16 + nlo) * A_STRIDE + quad * 8);

    // B fragments + MFMA: B[k = quad*8 + j][n = lane&15], read through the swizzle
    #pragma unroll
    for (int nt = 0; nt < 4; ++nt) {
      const int c = wave * 64 + nt * 16 + nlo;
      const int p = quad ^ ((c >> 1) & 3);
      const s16x8 bfr = *(const s16x8*)(Ws + c * BK + p * 8);
      #pragma unroll
      for (int mt = 0; mt < 4; ++mt)
        acc[mt][nt] = __builtin_amdgcn_mfma_f32_16x16x32_bf16(af[mt], bfr, acc[mt][nt], 0, 0, 0);
    }
  }

  __syncthreads();   // last chunk's reads done; LDS union about to be reused

  // per-row epilogue scalars (head gather of raw gate + sigmoid + masks)
  if (t < LTOK) {
    const int m  = b * LTOK + t;
    const int hd = arc[2 * m + 1];   // head token position (sent == b by construction)
    const int lb = lab[m];
    const float am = adj_mask_in[m];
    const float al = adj_mask_loop[m];
    winl[t] = sigmoidf_(gld[hd * 2 + 0] + b_gate_in[lb]) * am * am;
    wsfl[t] = sigmoidf_(gld[t * 2 + 1]) * al * al;
    mskl[t] = maskp[m];
    hdl[t]  = hd;
    lbl[t]  = lb;
  }

  // epilogue in two 128-col stages: P round-trips LDS as bf16 so the head-row
  // gather is a cheap LDS read; out = relu((Pin[hd]+b_in[lb])*w_in + Psf*w_self)*mask
  for (int s = 0; s < 2; ++s) {
    if (s) __syncthreads();          // stage-0 reads done before overwrite
    const int half = wave >> 2;      // 0 -> P_in cols, 1 -> P_self cols
    const int wcol = wave & 3;       // 64-col block within the half
    if ((wcol >> 1) == s) {
      unsigned short* dst = half ? Psf : Pin;
      const int cb = (wcol & 1) * 64;
      #pragma unroll
      for (int mt = 0; mt < 4; ++mt)
        #pragma unroll
        for (int nt = 0; nt < 4; ++nt)
          #pragma unroll
          for (int r = 0; r < 4; ++r) {
            const int row = mt * 16 + quad * 4 + r;   // C/D: row = quad*4 + reg
            const int col = cb + nt * 16 + nlo;       // C/D: col = lane&15
            dst[row * 128 + col] = f2bf(acc[mt][nt][r]);
          }
    }
    __syncthreads();
    #pragma unroll
    for (int i = 0; i < 4; ++i) {
      const int q   = i * TPB + t;
      const int row = q >> 5;
      const int cl  = (q & 31) * 4;
      const int cg  = s * 128 + cl;
      const int hd  = hdl[row];
      const int lb  = lbl[row];
      const float wi = winl[row], ws = wsfl[row], mk = mskl[row];
      const float4 bi = *(const float4*)(b_in + lb * DOUT + cg);
      const ushort4 pi = *(const ushort4*)(Pin + hd * 128 + cl);
      const ushort4 ps = *(const ushort4*)(Psf + row * 128 + cl);
      float4 v;
      v.x = (bf2f(pi.x) + bi.x) * wi + bf2f(ps.x) * ws;
      v.y = (bf2f(pi.y) + bi.y) * wi + bf2f(ps.y) * ws;
      v.z = (bf2f(pi.z) + bi.z) * wi + bf2f(ps.z) * ws;
      v.w = (bf2f(pi.w) + bi.w) * wi + bf2f(ps.w) * ws;
      v.x = fmaxf(v.x, 0.f) * mk; v.y = fmaxf(v.y, 0.f) * mk;
      v.z = fmaxf(v.z, 0.f) * mk; v.w = fmaxf(v.w, 0.f) * mk;
      *(float4*)(out + (size_t)(b * LTOK + row) * DOUT + cg) = v;
    }
  }
}

extern "C" void kernel_launch(void* const* d_in, const int* in_sizes, int n_in,
                              void* d_out, int out_size, void* d_ws, size_t ws_size,
                              hipStream_t stream) {
  const float* rep           = (const float*)d_in[0];
  const float* adj_mask_in   = (const float*)d_in[1];
  const float* adj_mask_loop = (const float*)d_in[2];
  const float* mask          = (const float*)d_in[3];
  const float* W_in          = (const float*)d_in[4];
  const float* b_in          = (const float*)d_in[5];
  const float* W_gate_in     = (const float*)d_in[6];
  const float* b_gate_in     = (const float*)d_in[7];
  const float* W_self        = (const float*)d_in[8];
  const float* W_gate_self   = (const float*)d_in[9];
  const int*   arc           = (const int*)d_in[10];
  const int*   lab           = (const int*)d_in[11];
  float* out = (float*)d_out;
  unsigned short* Wt = (unsigned short*)d_ws;   // [512][512] bf16, 512 KB

  wprep_kernel<<<256, 256, 0, stream>>>(W_in, W_self, Wt);
  gcn_kernel<<<BNK, TPB, 0, stream>>>(rep, adj_mask_in, adj_mask_loop, mask, b_in,
                                      W_gate_in, b_gate_in, W_gate_self, arc, lab, Wt, out);
}